// Round 8
// baseline (230.662 us; speedup 1.0000x reference)
//
#include <hip/hip_runtime.h>

#define N_NODES 50000
#define NCH 256          // edge chunks (blocks in count/scatter)
#define NBKT 256         // bucket slots (dst>>8; 196 live for N=50000)

typedef short bf16x8 __attribute__((ext_vector_type(8)));
typedef float f32x4 __attribute__((ext_vector_type(4)));

__device__ inline unsigned short f2bf(float f) {
    union { float f; unsigned u; } v; v.f = f;
    unsigned u = v.u;
    unsigned lsb = (u >> 16) & 1u;
    u += 0x7fffu + lsb;  // round-to-nearest-even
    return (unsigned short)(u >> 16);
}

__device__ inline float bf2f(unsigned short h) {
    union { unsigned u; float f; } v; v.u = ((unsigned)h) << 16;
    return v.f;
}

// ============ prep: bucket histogram (blocks < NCH) + W split (blocks >= NCH) ============
__global__ __launch_bounds__(256) void prep(const int* __restrict__ dst,
                                            int* __restrict__ cnt, int E, int epc,
                                            const float* __restrict__ W1,
                                            const float* __restrict__ W2,
                                            unsigned short* __restrict__ B1h,
                                            unsigned short* __restrict__ B1l,
                                            unsigned short* __restrict__ B2h,
                                            unsigned short* __restrict__ B2l) {
    const int c = blockIdx.x;
    if (c < NCH) {
        __shared__ int h[NBKT];
        h[threadIdx.x] = 0;
        __syncthreads();
        const int e0 = c * epc;
        const int e1 = min(E, e0 + epc);
        for (int e = e0 + threadIdx.x; e < e1; e += 256)
            atomicAdd(&h[dst[e] >> 8], 1);
        __syncthreads();
        cnt[c * NBKT + threadIdx.x] = h[threadIdx.x];
        return;
    }
    // W split into MFMA fragment order:
    // Bf[((g*KS+ks)*64 + quad*16 + n16)*8 + j] = bf16(W^T[g*16+n16][ks*32+quad*8+j])
    int i = (c - NCH) * 256 + threadIdx.x;
    const float* W;
    unsigned short *Th, *Tl;
    int K, logM, idx;
    if (i < 32768) { W = W1; Th = B1h; Tl = B1l; K = 256; logM = 7; idx = i; }
    else if (i < 32768 + 8192) { W = W2; Th = B2h; Tl = B2l; K = 128; logM = 6; idx = i - 32768; }
    else return;
    const int M = 1 << logM;
    const int KS = K / 32;
    int k = idx >> logM;
    int n = idx & (M - 1);
    float v = W[idx];
    unsigned short h = f2bf(v);
    unsigned short l = f2bf(v - bf2f(h));
    int g = n >> 4, n16 = n & 15, ks = k >> 5, quad = (k >> 3) & 3, j = k & 7;
    size_t o = ((size_t)((g * KS + ks) * 64 + quad * 16 + n16)) * 8 + j;
    Th[o] = h;
    Tl[o] = l;
}

// S1: per-bucket exclusive scan over chunks; off[c][b], total[b]
__global__ __launch_bounds__(256) void bkt_scan_chunks(const int* __restrict__ cnt,
                                                       int* __restrict__ off,
                                                       int* __restrict__ total) {
    __shared__ int sh[256];
    const int b = blockIdx.x;
    const int t = threadIdx.x;
    int v = cnt[t * NBKT + b];
    sh[t] = v;
    __syncthreads();
    for (int o = 1; o < 256; o <<= 1) {
        int u = (t >= o) ? sh[t - o] : 0;
        __syncthreads();
        sh[t] += u;
        __syncthreads();
    }
    off[t * NBKT + b] = sh[t] - v;
    if (t == 255) total[b] = sh[255];
}

// S2: scan totals -> bbase[0..256]; rowptr[N]=E
__global__ __launch_bounds__(256) void bkt_scan_base(const int* __restrict__ total,
                                                     int* __restrict__ bbase,
                                                     int* __restrict__ rowptr,
                                                     int N, int E) {
    __shared__ int sh[256];
    const int t = threadIdx.x;
    int v = total[t];
    sh[t] = v;
    __syncthreads();
    for (int o = 1; o < 256; o <<= 1) {
        int u = (t >= o) ? sh[t - o] : 0;
        __syncthreads();
        sh[t] += u;
        __syncthreads();
    }
    bbase[t] = sh[t] - v;
    if (t == 255) bbase[256] = sh[255];
    if (t == 0) rowptr[N] = E;
}

// B2: scatter packed (src<<8 | dst&255) into bucket-sorted order; LDS cursors
__global__ __launch_bounds__(256) void bkt_scatter(const int* __restrict__ src,
                                                   const int* __restrict__ dst,
                                                   const int* __restrict__ off,
                                                   const int* __restrict__ bbase,
                                                   unsigned* __restrict__ pairs,
                                                   int E, int epc) {
    __shared__ int cur[NBKT];
    const int c = blockIdx.x;
    cur[threadIdx.x] = bbase[threadIdx.x] + off[c * NBKT + threadIdx.x];
    __syncthreads();
    const int e0 = c * epc;
    const int e1 = min(E, e0 + epc);
    for (int e = e0 + threadIdx.x; e < e1; e += 256) {
        int s = src[e];
        int d = dst[e];
        int pos = atomicAdd(&cur[d >> 8], 1);
        pairs[pos] = ((unsigned)s << 8) | (unsigned)(d & 255);
    }
}

// B3: per-bucket local CSR: rowptr, dinv, csr_src (dense regional writes)
__global__ __launch_bounds__(256) void bkt_csr(const unsigned* __restrict__ pairs,
                                               const int* __restrict__ bbase,
                                               int* __restrict__ rowptr,
                                               int* __restrict__ csr_src,
                                               float* __restrict__ dinv, int N) {
    __shared__ int lh[256];
    __shared__ int sc[256];
    __shared__ int lcur[256];
    const int b = blockIdx.x;
    const int t = threadIdx.x;
    const int ebase = bbase[b];
    const int eend = bbase[b + 1];
    const int node0 = b << 8;

    lh[t] = 0;
    __syncthreads();
    for (int e = ebase + t; e < eend; e += 256)
        atomicAdd(&lh[pairs[e] & 255u], 1);
    __syncthreads();
    int v = lh[t];
    sc[t] = v;
    __syncthreads();
    for (int o = 1; o < 256; o <<= 1) {
        int u = (t >= o) ? sc[t - o] : 0;
        __syncthreads();
        sc[t] += u;
        __syncthreads();
    }
    const int excl = sc[t] - v;
    lcur[t] = ebase + excl;
    const int node = node0 + t;
    if (node < N) {
        rowptr[node] = ebase + excl;
        dinv[node] = rsqrtf((float)(v + 1));  // +1 self-loop
    }
    __syncthreads();
    for (int e = ebase + t; e < eend; e += 256) {
        unsigned p = pairs[e];
        int pos = atomicAdd(&lcur[p & 255u], 1);
        csr_src[pos] = (int)(p >> 8);
    }
}

// ============ MFMA GEMM v5: 32x32 patch/wave, rolling B, dbuf LDS A,
//              bf16 PANEL output (32-col panels) ============
// A fp32 addressing: elem(row, ks*32 + q8) at A[row*RS + ks*KSS + ...]
//   row-major:   RS=K,  KSS=32
//   panel-major: RS=32, KSS=N*32
template <int K, int M, int RS, long long KSS>
__global__ __launch_bounds__(M * 4) void gemm_mfma_v5(const float* __restrict__ A,
                                                      const unsigned short* __restrict__ Bfh,
                                                      const unsigned short* __restrict__ Bfl,
                                                      const float* __restrict__ dinv,
                                                      unsigned short* __restrict__ Cb, int N) {
    const int KS = K / 32;
    const int THREADS = M * 4;
    const int CPT = 512 / THREADS;
    const int PL = 64 * 40;
    const int CPAIRS = M / 32;

    __shared__ __align__(16) unsigned short Ah[2 * PL];
    __shared__ __align__(16) unsigned short Al[2 * PL];

    const int tid = threadIdx.x;
    const int wave = tid >> 6;
    const int lane = tid & 63;
    const int n16 = lane & 15;
    const int quad = lane >> 4;
    const int cpair = wave & (CPAIRS - 1);
    const int rpair = wave / CPAIRS;  // 0 or 1
    const int row0 = blockIdx.x * 64;

    // rolling B fragments: [parity][ct]
    bf16x8 bh[2][2], bl[2][2];
    auto loadB = [&](int ks, int par) {
#pragma unroll
        for (int ct = 0; ct < 2; ct++) {
            const int g = cpair * 2 + ct;
            const size_t o = ((size_t)(g * KS + ks) * 64 + lane) * 8;
            bh[par][ct] = *(const bf16x8*)(Bfh + o);
            bl[par][ct] = *(const bf16x8*)(Bfl + o);
        }
    };
    loadB(0, 0);

    // A staging (64 x 32 fp32 tile = 512 float4 chunks)
    int srow[CPT], sc4[CPT];
    const float* aptr[CPT];
#pragma unroll
    for (int p = 0; p < CPT; p++) {
        int q = p * THREADS + tid;
        srow[p] = q >> 3;
        sc4[p] = q & 7;
        int grow = row0 + srow[p];
        if (grow >= N) grow = N - 1;
        aptr[p] = A + (size_t)grow * RS + sc4[p] * 4;
    }

    float4 pre[CPT];
#pragma unroll
    for (int p = 0; p < CPT; p++) pre[p] = *(const float4*)(aptr[p]);

#pragma unroll
    for (int p = 0; p < CPT; p++) {
        ushort4 h4, l4;
        unsigned short* hp = (unsigned short*)&h4;
        unsigned short* lp = (unsigned short*)&l4;
        float av[4] = {pre[p].x, pre[p].y, pre[p].z, pre[p].w};
#pragma unroll
        for (int j = 0; j < 4; j++) {
            unsigned short h = f2bf(av[j]);
            hp[j] = h;
            lp[j] = f2bf(av[j] - bf2f(h));
        }
        *(ushort4*)(Ah + srow[p] * 40 + sc4[p] * 4) = h4;
        *(ushort4*)(Al + srow[p] * 40 + sc4[p] * 4) = l4;
    }
    if (KS > 1) {
#pragma unroll
        for (int p = 0; p < CPT; p++) pre[p] = *(const float4*)(aptr[p] + KSS);
    }
    __syncthreads();

    f32x4 acc[2][2] = {};

#pragma unroll
    for (int ks = 0; ks < KS; ks++) {
        const int cur = ks & 1;
        if (ks + 1 < KS) loadB(ks + 1, cur ^ 1);
#pragma unroll
        for (int rt = 0; rt < 2; rt++) {
            const int ro = cur * PL + (rpair * 32 + rt * 16 + n16) * 40 + quad * 8;
            bf16x8 ah = *(const bf16x8*)(Ah + ro);
            bf16x8 al = *(const bf16x8*)(Al + ro);
#pragma unroll
            for (int ct = 0; ct < 2; ct++) {
                acc[rt][ct] = __builtin_amdgcn_mfma_f32_16x16x32_bf16(ah, bh[cur][ct], acc[rt][ct], 0, 0, 0);
                acc[rt][ct] = __builtin_amdgcn_mfma_f32_16x16x32_bf16(ah, bl[cur][ct], acc[rt][ct], 0, 0, 0);
                acc[rt][ct] = __builtin_amdgcn_mfma_f32_16x16x32_bf16(al, bh[cur][ct], acc[rt][ct], 0, 0, 0);
            }
        }
        if (ks + 1 < KS) {
            const int nxt = (cur ^ 1) * PL;
#pragma unroll
            for (int p = 0; p < CPT; p++) {
                ushort4 h4, l4;
                unsigned short* hp = (unsigned short*)&h4;
                unsigned short* lp = (unsigned short*)&l4;
                float av[4] = {pre[p].x, pre[p].y, pre[p].z, pre[p].w};
#pragma unroll
                for (int j = 0; j < 4; j++) {
                    unsigned short h = f2bf(av[j]);
                    hp[j] = h;
                    lp[j] = f2bf(av[j] - bf2f(h));
                }
                *(ushort4*)(Ah + nxt + srow[p] * 40 + sc4[p] * 4) = h4;
                *(ushort4*)(Al + nxt + srow[p] * 40 + sc4[p] * 4) = l4;
            }
            if (ks + 2 < KS) {
#pragma unroll
                for (int p = 0; p < CPT; p++)
                    pre[p] = *(const float4*)(aptr[p] + (size_t)(ks + 2) * KSS);
            }
        }
        __syncthreads();
    }

    // epilogue: 32-col panel layout; panel = cpair; within-panel col = ct*16+n16
    // D mapping per 16x16 tile: col = lane&15, row = quad*4 + reg
#pragma unroll
    for (int rt = 0; rt < 2; rt++) {
        const int rbase = row0 + rpair * 32 + rt * 16 + quad * 4;
#pragma unroll
        for (int ct = 0; ct < 2; ct++) {
            const int pcol = ct * 16 + n16;
#pragma unroll
            for (int r = 0; r < 4; r++) {
                int orow = rbase + r;
                if (orow < N) {
                    Cb[((size_t)cpair * N + orow) * 32 + pcol] =
                        f2bf(dinv[orow] * acc[rt][ct][r]);
                }
            }
        }
    }
}

// ============ per-panel gather-aggregate (bf16 panel in, fp32 out) ============
// hpan: N x 32 bf16 (one panel). out[g, j*8..] = [relu](dinv*(sum + self) + bias)
// 4 lanes/node (8 cols each), 64 nodes/block.
template <bool RELU>
__global__ __launch_bounds__(256) void gather_panel(const unsigned short* __restrict__ hpan,
                                                    const int* __restrict__ rowptr,
                                                    const int* __restrict__ csr_src,
                                                    const float* __restrict__ dinv,
                                                    const float* __restrict__ bias,
                                                    float* __restrict__ outp,
                                                    int outstride, int n) {
    int g = blockIdx.x * 64 + (threadIdx.x >> 2);
    int j = threadIdx.x & 3;
    if (g >= n) return;

    float acc[8];
    {
        bf16x8 v = *(const bf16x8*)(hpan + (size_t)g * 32 + j * 8);  // self-loop
#pragma unroll
        for (int i = 0; i < 8; i++) acc[i] = bf2f((unsigned short)v[i]);
    }

    int e = rowptr[g];
    const int end = rowptr[g + 1];
    for (; e + 3 < end; e += 4) {
        int s0 = csr_src[e];
        int s1 = csr_src[e + 1];
        int s2 = csr_src[e + 2];
        int s3 = csr_src[e + 3];
        bf16x8 v0 = *(const bf16x8*)(hpan + (size_t)s0 * 32 + j * 8);
        bf16x8 v1 = *(const bf16x8*)(hpan + (size_t)s1 * 32 + j * 8);
        bf16x8 v2 = *(const bf16x8*)(hpan + (size_t)s2 * 32 + j * 8);
        bf16x8 v3 = *(const bf16x8*)(hpan + (size_t)s3 * 32 + j * 8);
#pragma unroll
        for (int i = 0; i < 8; i++) {
            acc[i] += (bf2f((unsigned short)v0[i]) + bf2f((unsigned short)v1[i])) +
                      (bf2f((unsigned short)v2[i]) + bf2f((unsigned short)v3[i]));
        }
    }
    for (; e < end; e++) {
        int s0 = csr_src[e];
        bf16x8 v0 = *(const bf16x8*)(hpan + (size_t)s0 * 32 + j * 8);
#pragma unroll
        for (int i = 0; i < 8; i++) acc[i] += bf2f((unsigned short)v0[i]);
    }

    const float s = dinv[g];
    float r[8];
#pragma unroll
    for (int i = 0; i < 8; i++) {
        r[i] = s * acc[i] + bias[j * 8 + i];
        if (RELU) r[i] = fmaxf(r[i], 0.0f);
    }
    float* op = outp + (size_t)g * outstride + j * 8;
    *(float4*)(op) = make_float4(r[0], r[1], r[2], r[3]);
    *(float4*)(op + 4) = make_float4(r[4], r[5], r[6], r[7]);
}

extern "C" void kernel_launch(void* const* d_in, const int* in_sizes, int n_in,
                              void* d_out, int out_size, void* d_ws, size_t ws_size,
                              hipStream_t stream) {
    const float* x  = (const float*)d_in[0];
    const int*   ei = (const int*)d_in[1];
    const float* W1 = (const float*)d_in[2];
    const float* b1 = (const float*)d_in[3];
    const float* W2 = (const float*)d_in[4];
    const float* b2 = (const float*)d_in[5];

    const int N = N_NODES;
    const int E = in_sizes[1] / 2;
    const int* src = ei;
    const int* dst = ei + E;

    char* ws = (char*)d_ws;
    size_t off = 0;
    auto carve = [&](size_t bytes) {
        char* p = ws + off;
        off += (bytes + 255) & ~(size_t)255;
        return p;
    };
    int*      cnt     = (int*)     carve((size_t)NCH * NBKT * 4);
    int*      offm    = (int*)     carve((size_t)NCH * NBKT * 4);
    int*      total   = (int*)     carve((size_t)NBKT * 4);
    int*      bbase   = (int*)     carve((size_t)(NBKT + 1) * 4);
    unsigned* pairs   = (unsigned*)carve((size_t)E * 4);
    int*      rowptr  = (int*)     carve((size_t)(N + 1) * 4);
    int*      csr_src = (int*)     carve((size_t)E * 4);
    float*    dinv    = (float*)   carve((size_t)N * 4);
    unsigned short* W1th = (unsigned short*)carve((size_t)256 * 128 * 2);
    unsigned short* W1tl = (unsigned short*)carve((size_t)256 * 128 * 2);
    unsigned short* W2th = (unsigned short*)carve((size_t)128 * 64 * 2);
    unsigned short* W2tl = (unsigned short*)carve((size_t)128 * 64 * 2);
    unsigned short* hn1b = (unsigned short*)carve((size_t)N * 128 * 2);  // 4 panels N x 32
    float*          h1   = (float*)carve((size_t)N * 128 * 4);           // 4 panels N x 32 fp32
    unsigned short* hn2b = hn1b;  // 2 panels N x 32; hn1b dead after gather1

    const int epc = (E + NCH - 1) / NCH;
    const int nbk = (N + 255) >> 8;  // 196 live buckets

    // ---- CSR build + weight split ----
    prep<<<NCH + 160, 256, 0, stream>>>(dst, cnt, E, epc, W1, W2, W1th, W1tl, W2th, W2tl);
    bkt_scan_chunks<<<NBKT, 256, 0, stream>>>(cnt, offm, total);
    bkt_scan_base<<<1, 256, 0, stream>>>(total, bbase, rowptr, N, E);
    bkt_scatter<<<NCH, 256, 0, stream>>>(src, dst, offm, bbase, pairs, E, epc);
    bkt_csr<<<nbk, 256, 0, stream>>>(pairs, bbase, rowptr, csr_src, dinv, N);

    const int GB = (N + 63) / 64;  // 782 blocks

    // ---- layer 1: hn1b panels = dinv * (x @ W1) ----
    gemm_mfma_v5<256, 128, 256, 32><<<GB, 512, 0, stream>>>(x, W1th, W1tl, dinv, hn1b, N);
    // gather per panel (panel = 3.2 MB, L2-resident per pass)
    for (int p = 0; p < 4; p++) {
        gather_panel<true><<<GB, 256, 0, stream>>>(
            hn1b + (size_t)p * N * 32, rowptr, csr_src, dinv, b1 + p * 32,
            h1 + (size_t)p * N * 32, 32, N);
    }

    // ---- layer 2: hn2b panels = dinv * (h1 @ W2); h1 panels ARE the K-slices ----
    gemm_mfma_v5<128, 64, 32, (long long)N_NODES * 32><<<GB, 256, 0, stream>>>(
        h1, W2th, W2tl, dinv, hn2b, N);
    for (int p = 0; p < 2; p++) {
        gather_panel<false><<<GB, 256, 0, stream>>>(
            hn2b + (size_t)p * N * 32, rowptr, csr_src, dinv, b2 + p * 32,
            (float*)d_out + p * 32, 64, N);
    }
}

// Round 9
// 196.063 us; speedup vs baseline: 1.1765x; 1.1765x over previous
//
#include <hip/hip_runtime.h>

#define N_NODES 50000
#define NCH 256          // edge chunks (blocks in count/scatter)
#define NBKT 256         // bucket slots (dst>>8; 196 live for N=50000)

typedef short bf16x8 __attribute__((ext_vector_type(8)));
typedef float f32x4 __attribute__((ext_vector_type(4)));

__device__ inline unsigned short f2bf(float f) {
    union { float f; unsigned u; } v; v.f = f;
    unsigned u = v.u;
    unsigned lsb = (u >> 16) & 1u;
    u += 0x7fffu + lsb;  // round-to-nearest-even
    return (unsigned short)(u >> 16);
}

__device__ inline float bf2f(unsigned short h) {
    union { unsigned u; float f; } v; v.u = ((unsigned)h) << 16;
    return v.f;
}

// ============ prep: bucket histogram (blocks < NCH) + W split (blocks >= NCH) ============
__global__ __launch_bounds__(256) void prep(const int* __restrict__ dst,
                                            int* __restrict__ cnt, int E, int epc,
                                            const float* __restrict__ W1,
                                            const float* __restrict__ W2,
                                            unsigned short* __restrict__ B1h,
                                            unsigned short* __restrict__ B1l,
                                            unsigned short* __restrict__ B2h,
                                            unsigned short* __restrict__ B2l) {
    const int c = blockIdx.x;
    if (c < NCH) {
        __shared__ int h[NBKT];
        h[threadIdx.x] = 0;
        __syncthreads();
        const int e0 = c * epc;
        const int e1 = min(E, e0 + epc);
        for (int e = e0 + threadIdx.x; e < e1; e += 256)
            atomicAdd(&h[dst[e] >> 8], 1);
        __syncthreads();
        cnt[c * NBKT + threadIdx.x] = h[threadIdx.x];
        return;
    }
    // W split into MFMA fragment order:
    // Bf[((g*KS+ks)*64 + quad*16 + n16)*8 + j] = bf16(W^T[g*16+n16][ks*32+quad*8+j])
    int i = (c - NCH) * 256 + threadIdx.x;
    const float* W;
    unsigned short *Th, *Tl;
    int K, logM, idx;
    if (i < 32768) { W = W1; Th = B1h; Tl = B1l; K = 256; logM = 7; idx = i; }
    else if (i < 32768 + 8192) { W = W2; Th = B2h; Tl = B2l; K = 128; logM = 6; idx = i - 32768; }
    else return;
    const int M = 1 << logM;
    const int KS = K / 32;
    int k = idx >> logM;
    int n = idx & (M - 1);
    float v = W[idx];
    unsigned short h = f2bf(v);
    unsigned short l = f2bf(v - bf2f(h));
    int g = n >> 4, n16 = n & 15, ks = k >> 5, quad = (k >> 3) & 3, j = k & 7;
    size_t o = ((size_t)((g * KS + ks) * 64 + quad * 16 + n16)) * 8 + j;
    Th[o] = h;
    Tl[o] = l;
}

// S1: per-bucket exclusive scan over chunks; off[c][b], total[b]
__global__ __launch_bounds__(256) void bkt_scan_chunks(const int* __restrict__ cnt,
                                                       int* __restrict__ off,
                                                       int* __restrict__ total) {
    __shared__ int sh[256];
    const int b = blockIdx.x;
    const int t = threadIdx.x;
    int v = cnt[t * NBKT + b];
    sh[t] = v;
    __syncthreads();
    for (int o = 1; o < 256; o <<= 1) {
        int u = (t >= o) ? sh[t - o] : 0;
        __syncthreads();
        sh[t] += u;
        __syncthreads();
    }
    off[t * NBKT + b] = sh[t] - v;
    if (t == 255) total[b] = sh[255];
}

// S2: scan totals -> bbase[0..256]; rowptr[N]=E
__global__ __launch_bounds__(256) void bkt_scan_base(const int* __restrict__ total,
                                                     int* __restrict__ bbase,
                                                     int* __restrict__ rowptr,
                                                     int N, int E) {
    __shared__ int sh[256];
    const int t = threadIdx.x;
    int v = total[t];
    sh[t] = v;
    __syncthreads();
    for (int o = 1; o < 256; o <<= 1) {
        int u = (t >= o) ? sh[t - o] : 0;
        __syncthreads();
        sh[t] += u;
        __syncthreads();
    }
    bbase[t] = sh[t] - v;
    if (t == 255) bbase[256] = sh[255];
    if (t == 0) rowptr[N] = E;
}

// B2: scatter packed (src<<8 | dst&255) into bucket-sorted order; LDS cursors
__global__ __launch_bounds__(256) void bkt_scatter(const int* __restrict__ src,
                                                   const int* __restrict__ dst,
                                                   const int* __restrict__ off,
                                                   const int* __restrict__ bbase,
                                                   unsigned* __restrict__ pairs,
                                                   int E, int epc) {
    __shared__ int cur[NBKT];
    const int c = blockIdx.x;
    cur[threadIdx.x] = bbase[threadIdx.x] + off[c * NBKT + threadIdx.x];
    __syncthreads();
    const int e0 = c * epc;
    const int e1 = min(E, e0 + epc);
    for (int e = e0 + threadIdx.x; e < e1; e += 256) {
        int s = src[e];
        int d = dst[e];
        int pos = atomicAdd(&cur[d >> 8], 1);
        pairs[pos] = ((unsigned)s << 8) | (unsigned)(d & 255);
    }
}

// B3: per-bucket local CSR: rowptr, dinv, csr_src (dense regional writes)
__global__ __launch_bounds__(256) void bkt_csr(const unsigned* __restrict__ pairs,
                                               const int* __restrict__ bbase,
                                               int* __restrict__ rowptr,
                                               int* __restrict__ csr_src,
                                               float* __restrict__ dinv, int N) {
    __shared__ int lh[256];
    __shared__ int sc[256];
    __shared__ int lcur[256];
    const int b = blockIdx.x;
    const int t = threadIdx.x;
    const int ebase = bbase[b];
    const int eend = bbase[b + 1];
    const int node0 = b << 8;

    lh[t] = 0;
    __syncthreads();
    for (int e = ebase + t; e < eend; e += 256)
        atomicAdd(&lh[pairs[e] & 255u], 1);
    __syncthreads();
    int v = lh[t];
    sc[t] = v;
    __syncthreads();
    for (int o = 1; o < 256; o <<= 1) {
        int u = (t >= o) ? sc[t - o] : 0;
        __syncthreads();
        sc[t] += u;
        __syncthreads();
    }
    const int excl = sc[t] - v;
    lcur[t] = ebase + excl;
    const int node = node0 + t;
    if (node < N) {
        rowptr[node] = ebase + excl;
        dinv[node] = rsqrtf((float)(v + 1));  // +1 self-loop
    }
    __syncthreads();
    for (int e = ebase + t; e < eend; e += 256) {
        unsigned p = pairs[e];
        int pos = atomicAdd(&lcur[p & 255u], 1);
        csr_src[pos] = (int)(p >> 8);
    }
}

// ============ MFMA GEMM (layer1): fp32 A -> 3-term split, 32x32/wave,
//              rolling B, dbuf LDS, bf16 monolithic out ============
template <int K, int M>
__global__ __launch_bounds__(M * 4) void gemm_mfma_v4(const float* __restrict__ A,
                                                      const unsigned short* __restrict__ Bfh,
                                                      const unsigned short* __restrict__ Bfl,
                                                      const float* __restrict__ dinv,
                                                      unsigned short* __restrict__ Cb, int N) {
    const int KS = K / 32;
    const int THREADS = M * 4;
    const int CPT = 512 / THREADS;
    const int PL = 64 * 40;
    const int CPAIRS = M / 32;

    __shared__ __align__(16) unsigned short Ah[2 * PL];
    __shared__ __align__(16) unsigned short Al[2 * PL];

    const int tid = threadIdx.x;
    const int wave = tid >> 6;
    const int lane = tid & 63;
    const int n16 = lane & 15;
    const int quad = lane >> 4;
    const int cpair = wave & (CPAIRS - 1);
    const int rpair = wave / CPAIRS;
    const int row0 = blockIdx.x * 64;

    bf16x8 bh[2][2], bl[2][2];
    auto loadB = [&](int ks, int par) {
#pragma unroll
        for (int ct = 0; ct < 2; ct++) {
            const int g = cpair * 2 + ct;
            const size_t o = ((size_t)(g * KS + ks) * 64 + lane) * 8;
            bh[par][ct] = *(const bf16x8*)(Bfh + o);
            bl[par][ct] = *(const bf16x8*)(Bfl + o);
        }
    };
    loadB(0, 0);

    int srow[CPT], sc4[CPT];
    const float* aptr[CPT];
#pragma unroll
    for (int p = 0; p < CPT; p++) {
        int q = p * THREADS + tid;
        srow[p] = q >> 3;
        sc4[p] = q & 7;
        int grow = row0 + srow[p];
        if (grow >= N) grow = N - 1;
        aptr[p] = A + (size_t)grow * K + sc4[p] * 4;
    }

    float4 pre[CPT];
#pragma unroll
    for (int p = 0; p < CPT; p++) pre[p] = *(const float4*)(aptr[p]);

#pragma unroll
    for (int p = 0; p < CPT; p++) {
        ushort4 h4, l4;
        unsigned short* hp = (unsigned short*)&h4;
        unsigned short* lp = (unsigned short*)&l4;
        float av[4] = {pre[p].x, pre[p].y, pre[p].z, pre[p].w};
#pragma unroll
        for (int j = 0; j < 4; j++) {
            unsigned short h = f2bf(av[j]);
            hp[j] = h;
            lp[j] = f2bf(av[j] - bf2f(h));
        }
        *(ushort4*)(Ah + srow[p] * 40 + sc4[p] * 4) = h4;
        *(ushort4*)(Al + srow[p] * 40 + sc4[p] * 4) = l4;
    }
    if (KS > 1) {
#pragma unroll
        for (int p = 0; p < CPT; p++) pre[p] = *(const float4*)(aptr[p] + 32);
    }
    __syncthreads();

    f32x4 acc[2][2] = {};

#pragma unroll
    for (int ks = 0; ks < KS; ks++) {
        const int cur = ks & 1;
        if (ks + 1 < KS) loadB(ks + 1, cur ^ 1);
#pragma unroll
        for (int rt = 0; rt < 2; rt++) {
            const int ro = cur * PL + (rpair * 32 + rt * 16 + n16) * 40 + quad * 8;
            bf16x8 ah = *(const bf16x8*)(Ah + ro);
            bf16x8 al = *(const bf16x8*)(Al + ro);
#pragma unroll
            for (int ct = 0; ct < 2; ct++) {
                acc[rt][ct] = __builtin_amdgcn_mfma_f32_16x16x32_bf16(ah, bh[cur][ct], acc[rt][ct], 0, 0, 0);
                acc[rt][ct] = __builtin_amdgcn_mfma_f32_16x16x32_bf16(ah, bl[cur][ct], acc[rt][ct], 0, 0, 0);
                acc[rt][ct] = __builtin_amdgcn_mfma_f32_16x16x32_bf16(al, bh[cur][ct], acc[rt][ct], 0, 0, 0);
            }
        }
        if (ks + 1 < KS) {
            const int nxt = (cur ^ 1) * PL;
#pragma unroll
            for (int p = 0; p < CPT; p++) {
                ushort4 h4, l4;
                unsigned short* hp = (unsigned short*)&h4;
                unsigned short* lp = (unsigned short*)&l4;
                float av[4] = {pre[p].x, pre[p].y, pre[p].z, pre[p].w};
#pragma unroll
                for (int j = 0; j < 4; j++) {
                    unsigned short h = f2bf(av[j]);
                    hp[j] = h;
                    lp[j] = f2bf(av[j] - bf2f(h));
                }
                *(ushort4*)(Ah + nxt + srow[p] * 40 + sc4[p] * 4) = h4;
                *(ushort4*)(Al + nxt + srow[p] * 40 + sc4[p] * 4) = l4;
            }
            if (ks + 2 < KS) {
#pragma unroll
                for (int p = 0; p < CPT; p++)
                    pre[p] = *(const float4*)(aptr[p] + (ks + 2) * 32);
            }
        }
        __syncthreads();
    }

#pragma unroll
    for (int rt = 0; rt < 2; rt++) {
#pragma unroll
        for (int ct = 0; ct < 2; ct++) {
            const int col = cpair * 32 + ct * 16 + n16;
            const int rbase = row0 + rpair * 32 + rt * 16 + quad * 4;
#pragma unroll
            for (int r = 0; r < 4; r++) {
                int orow = rbase + r;
                if (orow < N) {
                    Cb[(size_t)orow * M + col] = f2bf(dinv[orow] * acc[rt][ct][r]);
                }
            }
        }
    }
}

// ============ MFMA GEMM (layer2): bf16 A direct-stage (no split), 2 MFMA/step ============
template <int K, int M>
__global__ __launch_bounds__(M * 4) void gemm_mfma_bfA(const unsigned short* __restrict__ A,
                                                       const unsigned short* __restrict__ Bfh,
                                                       const unsigned short* __restrict__ Bfl,
                                                       const float* __restrict__ dinv,
                                                       unsigned short* __restrict__ Cb, int N) {
    const int KS = K / 32;
    const int THREADS = M * 4;                 // 256 for M=64
    const int CPT = 256 / THREADS ? 256 / THREADS : 1;  // 64x32 bf16 tile = 256 x 16B chunks
    const int PL = 64 * 40;
    const int CPAIRS = M / 32;

    __shared__ __align__(16) unsigned short Ah[2 * PL];

    const int tid = threadIdx.x;
    const int wave = tid >> 6;
    const int lane = tid & 63;
    const int n16 = lane & 15;
    const int quad = lane >> 4;
    const int cpair = wave & (CPAIRS - 1);
    const int rpair = wave / CPAIRS;
    const int row0 = blockIdx.x * 64;

    bf16x8 bh[2][2], bl[2][2];
    auto loadB = [&](int ks, int par) {
#pragma unroll
        for (int ct = 0; ct < 2; ct++) {
            const int g = cpair * 2 + ct;
            const size_t o = ((size_t)(g * KS + ks) * 64 + lane) * 8;
            bh[par][ct] = *(const bf16x8*)(Bfh + o);
            bl[par][ct] = *(const bf16x8*)(Bfl + o);
        }
    };
    loadB(0, 0);

    // A staging: 64 rows x 32 cols bf16 = 256 chunks of 8 ushorts
    // chunk q: row = q>>2, c8 = q&3
    const int srow = tid >> 2;
    const int sc8 = tid & 3;
    const unsigned short* aptr;
    {
        int grow = row0 + srow;
        if (grow >= N) grow = N - 1;
        aptr = A + (size_t)grow * K + sc8 * 8;
    }

    bf16x8 pre = *(const bf16x8*)(aptr);

    // store tile 0 (two 8B writes: 80B row stride keeps 8B alignment)
    {
        ushort4* d0 = (ushort4*)(Ah + srow * 40 + sc8 * 8);
        ushort4 lo, hi;
        unsigned short* lp = (unsigned short*)&lo;
        unsigned short* hp = (unsigned short*)&hi;
#pragma unroll
        for (int j = 0; j < 4; j++) { lp[j] = (unsigned short)pre[j]; hp[j] = (unsigned short)pre[j + 4]; }
        d0[0] = lo;
        d0[1] = hi;
    }
    if (KS > 1) pre = *(const bf16x8*)(aptr + 32);
    __syncthreads();

    f32x4 acc[2][2] = {};

#pragma unroll
    for (int ks = 0; ks < KS; ks++) {
        const int cur = ks & 1;
        if (ks + 1 < KS) loadB(ks + 1, cur ^ 1);
#pragma unroll
        for (int rt = 0; rt < 2; rt++) {
            const int ro = cur * PL + (rpair * 32 + rt * 16 + n16) * 40 + quad * 8;
            bf16x8 ah = *(const bf16x8*)(Ah + ro);
#pragma unroll
            for (int ct = 0; ct < 2; ct++) {
                acc[rt][ct] = __builtin_amdgcn_mfma_f32_16x16x32_bf16(ah, bh[cur][ct], acc[rt][ct], 0, 0, 0);
                acc[rt][ct] = __builtin_amdgcn_mfma_f32_16x16x32_bf16(ah, bl[cur][ct], acc[rt][ct], 0, 0, 0);
            }
        }
        if (ks + 1 < KS) {
            const int nxt = (cur ^ 1) * PL;
            ushort4* d0 = (ushort4*)(Ah + nxt + srow * 40 + sc8 * 8);
            ushort4 lo, hi;
            unsigned short* lp = (unsigned short*)&lo;
            unsigned short* hp = (unsigned short*)&hi;
#pragma unroll
            for (int j = 0; j < 4; j++) { lp[j] = (unsigned short)pre[j]; hp[j] = (unsigned short)pre[j + 4]; }
            d0[0] = lo;
            d0[1] = hi;
            if (ks + 2 < KS) pre = *(const bf16x8*)(aptr + (ks + 2) * 32);
        }
        __syncthreads();
    }

#pragma unroll
    for (int rt = 0; rt < 2; rt++) {
#pragma unroll
        for (int ct = 0; ct < 2; ct++) {
            const int col = cpair * 32 + ct * 16 + n16;
            const int rbase = row0 + rpair * 32 + rt * 16 + quad * 4;
#pragma unroll
            for (int r = 0; r < 4; r++) {
                int orow = rbase + r;
                if (orow < N) {
                    Cb[(size_t)orow * M + col] = f2bf(dinv[orow] * acc[rt][ct][r]);
                }
            }
        }
    }
}

// ============ gather-aggregate (bf16 rows in) -> bf16 out (+ReLU) ============
template <int M>
__global__ __launch_bounds__(256) void gather_to_bf16(const unsigned short* __restrict__ hnb,
                                                      const int* __restrict__ rowptr,
                                                      const int* __restrict__ csr_src,
                                                      const float* __restrict__ dinv,
                                                      const float* __restrict__ bias,
                                                      unsigned short* __restrict__ outp, int n) {
    const int MQ = M / 8;
    const int GPB = 256 / MQ;
    int g = blockIdx.x * GPB + threadIdx.x / MQ;
    int j = threadIdx.x % MQ;
    if (g >= n) return;

    float acc[8];
    {
        bf16x8 v = *(const bf16x8*)(hnb + (size_t)g * M + j * 8);  // self-loop
#pragma unroll
        for (int i = 0; i < 8; i++) acc[i] = bf2f((unsigned short)v[i]);
    }

    int e = rowptr[g];
    const int end = rowptr[g + 1];
    for (; e + 3 < end; e += 4) {
        int s0 = csr_src[e];
        int s1 = csr_src[e + 1];
        int s2 = csr_src[e + 2];
        int s3 = csr_src[e + 3];
        bf16x8 v0 = *(const bf16x8*)(hnb + (size_t)s0 * M + j * 8);
        bf16x8 v1 = *(const bf16x8*)(hnb + (size_t)s1 * M + j * 8);
        bf16x8 v2 = *(const bf16x8*)(hnb + (size_t)s2 * M + j * 8);
        bf16x8 v3 = *(const bf16x8*)(hnb + (size_t)s3 * M + j * 8);
#pragma unroll
        for (int i = 0; i < 8; i++) {
            acc[i] += (bf2f((unsigned short)v0[i]) + bf2f((unsigned short)v1[i])) +
                      (bf2f((unsigned short)v2[i]) + bf2f((unsigned short)v3[i]));
        }
    }
    for (; e < end; e++) {
        int s0 = csr_src[e];
        bf16x8 v0 = *(const bf16x8*)(hnb + (size_t)s0 * M + j * 8);
#pragma unroll
        for (int i = 0; i < 8; i++) acc[i] += bf2f((unsigned short)v0[i]);
    }

    const float s = dinv[g];
    bf16x8 r;
#pragma unroll
    for (int i = 0; i < 8; i++) {
        float t = fmaxf(s * acc[i] + bias[j * 8 + i], 0.0f);  // ReLU
        r[i] = (short)f2bf(t);
    }
    *(bf16x8*)(outp + (size_t)g * M + j * 8) = r;
}

// ============ gather-aggregate (bf16 rows in) -> fp32 out (no ReLU) ============
template <int M>
__global__ __launch_bounds__(256) void gather_to_f32(const unsigned short* __restrict__ hnb,
                                                     const int* __restrict__ rowptr,
                                                     const int* __restrict__ csr_src,
                                                     const float* __restrict__ dinv,
                                                     const float* __restrict__ bias,
                                                     float* __restrict__ outp, int n) {
    const int MQ = M / 8;
    const int GPB = 256 / MQ;
    int g = blockIdx.x * GPB + threadIdx.x / MQ;
    int j = threadIdx.x % MQ;
    if (g >= n) return;

    float acc[8];
    {
        bf16x8 v = *(const bf16x8*)(hnb + (size_t)g * M + j * 8);  // self-loop
#pragma unroll
        for (int i = 0; i < 8; i++) acc[i] = bf2f((unsigned short)v[i]);
    }

    int e = rowptr[g];
    const int end = rowptr[g + 1];
    for (; e + 3 < end; e += 4) {
        int s0 = csr_src[e];
        int s1 = csr_src[e + 1];
        int s2 = csr_src[e + 2];
        int s3 = csr_src[e + 3];
        bf16x8 v0 = *(const bf16x8*)(hnb + (size_t)s0 * M + j * 8);
        bf16x8 v1 = *(const bf16x8*)(hnb + (size_t)s1 * M + j * 8);
        bf16x8 v2 = *(const bf16x8*)(hnb + (size_t)s2 * M + j * 8);
        bf16x8 v3 = *(const bf16x8*)(hnb + (size_t)s3 * M + j * 8);
#pragma unroll
        for (int i = 0; i < 8; i++) {
            acc[i] += (bf2f((unsigned short)v0[i]) + bf2f((unsigned short)v1[i])) +
                      (bf2f((unsigned short)v2[i]) + bf2f((unsigned short)v3[i]));
        }
    }
    for (; e < end; e++) {
        int s0 = csr_src[e];
        bf16x8 v0 = *(const bf16x8*)(hnb + (size_t)s0 * M + j * 8);
#pragma unroll
        for (int i = 0; i < 8; i++) acc[i] += bf2f((unsigned short)v0[i]);
    }

    const float s = dinv[g];
    float r[8];
#pragma unroll
    for (int i = 0; i < 8; i++) r[i] = s * acc[i] + bias[j * 8 + i];
    float* op = outp + (size_t)g * M + j * 8;
    *(float4*)(op) = make_float4(r[0], r[1], r[2], r[3]);
    *(float4*)(op + 4) = make_float4(r[4], r[5], r[6], r[7]);
}

extern "C" void kernel_launch(void* const* d_in, const int* in_sizes, int n_in,
                              void* d_out, int out_size, void* d_ws, size_t ws_size,
                              hipStream_t stream) {
    const float* x  = (const float*)d_in[0];
    const int*   ei = (const int*)d_in[1];
    const float* W1 = (const float*)d_in[2];
    const float* b1 = (const float*)d_in[3];
    const float* W2 = (const float*)d_in[4];
    const float* b2 = (const float*)d_in[5];

    const int N = N_NODES;
    const int E = in_sizes[1] / 2;
    const int* src = ei;
    const int* dst = ei + E;

    char* ws = (char*)d_ws;
    size_t off = 0;
    auto carve = [&](size_t bytes) {
        char* p = ws + off;
        off += (bytes + 255) & ~(size_t)255;
        return p;
    };
    int*      cnt     = (int*)     carve((size_t)NCH * NBKT * 4);
    int*      offm    = (int*)     carve((size_t)NCH * NBKT * 4);
    int*      total   = (int*)     carve((size_t)NBKT * 4);
    int*      bbase   = (int*)     carve((size_t)(NBKT + 1) * 4);
    unsigned* pairs   = (unsigned*)carve((size_t)E * 4);
    int*      rowptr  = (int*)     carve((size_t)(N + 1) * 4);
    int*      csr_src = (int*)     carve((size_t)E * 4);
    float*    dinv    = (float*)   carve((size_t)N * 4);
    unsigned short* W1th = (unsigned short*)carve((size_t)256 * 128 * 2);
    unsigned short* W1tl = (unsigned short*)carve((size_t)256 * 128 * 2);
    unsigned short* W2th = (unsigned short*)carve((size_t)128 * 64 * 2);
    unsigned short* W2tl = (unsigned short*)carve((size_t)128 * 64 * 2);
    unsigned short* hn1b = (unsigned short*)carve((size_t)N * 128 * 2);  // bf16
    unsigned short* h1b  = (unsigned short*)carve((size_t)N * 128 * 2);  // bf16
    unsigned short* hn2b = hn1b;  // hn1b dead after gather1

    const int epc = (E + NCH - 1) / NCH;
    const int nbk = (N + 255) >> 8;  // 196 live buckets

    // ---- CSR build + weight split ----
    prep<<<NCH + 160, 256, 0, stream>>>(dst, cnt, E, epc, W1, W2, W1th, W1tl, W2th, W2tl);
    bkt_scan_chunks<<<NBKT, 256, 0, stream>>>(cnt, offm, total);
    bkt_scan_base<<<1, 256, 0, stream>>>(total, bbase, rowptr, N, E);
    bkt_scatter<<<NCH, 256, 0, stream>>>(src, dst, offm, bbase, pairs, E, epc);
    bkt_csr<<<nbk, 256, 0, stream>>>(pairs, bbase, rowptr, csr_src, dinv, N);

    const int GB = (N + 63) / 64;  // 782 blocks

    // ---- layer 1 ----
    gemm_mfma_v4<256, 128><<<GB, 512, 0, stream>>>(x, W1th, W1tl, dinv, hn1b, N);
    {
        const int GPB = 256 / (128 / 8);  // 16 nodes/block
        gather_to_bf16<128><<<(N + GPB - 1) / GPB, 256, 0, stream>>>(
            hn1b, rowptr, csr_src, dinv, b1, h1b, N);
    }

    // ---- layer 2 ----
    gemm_mfma_bfA<128, 64><<<GB, 256, 0, stream>>>(h1b, W2th, W2tl, dinv, hn2b, N);
    {
        const int GPB = 256 / (64 / 8);  // 32 nodes/block
        gather_to_f32<64><<<(N + GPB - 1) / GPB, 256, 0, stream>>>(
            hn2b, rowptr, csr_src, dinv, b2, (float*)d_out, N);
    }
}